// Round 7
// baseline (2295.408 us; speedup 1.0000x reference)
//
#include <hip/hip_runtime.h>
#include <stdint.h>

// ProgressiveVQ: 8-stage residual VQ, T=131072 rows, D=256, K=1024 codewords/stage.
// out[0:T*D] = recon ; out[T*D..+8] = per-stage MSE (= mean(residual_i^2)).
//
// R7: SUPERPERIOD schedule at the proven-no-spill R1 register set.
//   * 4 waves/block, 64 rows/wave (TWO 32-row m-tiles), 2 blocks/CU.
//   * 64 codewords per period: ONE barrier + ONE vmcnt(0) per 128 MFMAs/wave
//     (half R1's sync rate). Two 32-cw groups computed sequentially, REUSING
//     one acc pair (R4's 4-acc variant spilled catastrophically).
//   * 2 x 32KB LDS buffers, 1 barrier/period safety: staging for period p+1
//     is issued at the TOP of p into buf[(p+1)&1]; that buffer's readers were
//     period p-1 and every wave issuing has passed barrier(p) which follows
//     those reads. The bottom vmcnt(0) guarantees each wave's staging has
//     landed before it reaches barrier(p+1).
//   * restart-fill fix: wave stages exactly fragments (grp g0=wave>>1,
//     s = s0..s0+7, s0=(wave&1)*8). At the bottom of p (after vmcnt(0)) it
//     pre-reads ITS OWN first 4 fragments of p+1 into registers, so MFMAs
//     issue immediately after the barrier while the ds_read burst queues.
//   * af stored WAVE-ROTATED: af[t][k] holds dim-slice s=(s0+k)&15 so every
//     register index is compile-time (rule #20); B addresses carry the
//     runtime rotation. MFMA s-order is commutative over k.
//   * flat B-FRAGMENT global layout (R6): staging linear, ds_reads linear
//     conflict-free, prep write-coalesced; cnorm read straight from global.
//   * acc zero-init; -||c||^2/2 deferred to pack; fmax-only argmax with the
//     codeword index packed into the low 10 mantissa bits.
//   bf16-carried residual (argmin near-ties only; validated earlier,
//   absmax <=4.5e-3). ||r||^2 recursion gives MSE free.

#define T_ROWS   131072
#define DIM      256
#define NSTAGE   8
#define NCB      1024
#define WROWS    64             // rows per wave (2 m-tiles of 32)
#define BLK_ROWS 256            // rows per block (4 waves)
#define NTHREADS 256
#define SUPER_CW 64             // codewords per period (2 groups of 32)
#define NPER_ST  (NCB / SUPER_CW)        // 16 periods/stage
#define NPER_ALL (NSTAGE * NPER_ST)      // 128 flat periods
#define SUPER_BYTES (SUPER_CW * 512)     // 32768

// d_ws layout
#define WS_B_BYTES     (NSTAGE * NCB * 512)            // bf16 codebook, B-frag layout, 4 MiB
#define WS_CNORM_OFF   WS_B_BYTES
#define WS_CNORM_BYTES (NSTAGE * NCB * 4)
#define WS_MSE_OFF     (WS_CNORM_OFF + WS_CNORM_BYTES)
#define WS_IDX_OFF     (WS_MSE_OFF + 64)               // u16[NSTAGE][T_ROWS], 2 MiB

typedef __attribute__((ext_vector_type(8)))  short  s16x8;
typedef __attribute__((ext_vector_type(8)))  __bf16 bf16x8;
typedef __attribute__((ext_vector_type(4)))  float  f32x4;
typedef __attribute__((ext_vector_type(16))) float  f32x16;

__device__ __forceinline__ unsigned short f2bf(float f) {
  union { float f; unsigned u; } v; v.f = f;
  unsigned r = v.u + 0x7FFFu + ((v.u >> 16) & 1u);   // RNE
  return (unsigned short)(r >> 16);
}

// ---------------------------------------------------------------------------
// Preprocess (R6, write-coalesced). Phase 1: fp32 CB -> bf16 B-frag copy.
//   block b (0..1023): group g = b>>2 (32 codewords), s-quarter s0q = (b&3)*4.
//   thread: c32 = tid&31, sh = tid>>5 -> s = s0q + (sh>>1), hi = sh&1.
//   dst = wsb + g*16384 + s*1024 + hi*512 + c32*16 (contiguous 4KB per block).
// Phase 2: cnorm with coalesced reads + 32-thread shfl reduction.
// ---------------------------------------------------------------------------
__global__ void vq_prep(const float* __restrict__ CB, char* __restrict__ wsb,
                        float* __restrict__ cnorm) {
  const int tid = threadIdx.x;
  const int b   = blockIdx.x;
  // ---- phase 1: B-frag copy ----
  {
    const int g   = b >> 2;
    const int s0q = (b & 3) * 4;
    const int c32 = tid & 31;
    const int sh  = tid >> 5;
    const int s   = s0q + (sh >> 1);
    const int hi  = sh & 1;
    const int cw  = g * 32 + c32;          // global codeword (stage built in)
    const float* src = CB + (size_t)cw * DIM + 16 * s + 8 * hi;
    f32x4 a = *(const f32x4*)(src);
    f32x4 c = *(const f32x4*)(src + 4);
    s16x8 h;
#pragma unroll
    for (int e = 0; e < 4; ++e) { h[e] = (short)f2bf(a[e]); h[4 + e] = (short)f2bf(c[e]); }
    *(s16x8*)(wsb + (size_t)g * 16384 + s * 1024 + hi * 512 + c32 * 16) = h;
  }
  // ---- phase 2: cnorm ----
  {
    const int cwl = tid >> 5;
    const int j   = tid & 31;
    const int cw  = b * 8 + cwl;
    const float* src = CB + (size_t)cw * DIM + 8 * j;
    f32x4 a = *(const f32x4*)(src);
    f32x4 c = *(const f32x4*)(src + 4);
    float sq = a[0]*a[0] + a[1]*a[1] + a[2]*a[2] + a[3]*a[3]
             + c[0]*c[0] + c[1]*c[1] + c[2]*c[2] + c[3]*c[3];
#pragma unroll
    for (int m = 1; m <= 16; m <<= 1) sq += __shfl_xor(sq, m);   // 32-thread group
    if (j == 0) cnorm[cw] = sq;
  }
}

// ---------------------------------------------------------------------------
// Search kernel. 4 waves/block; wave owns 64 rows as TWO 32-row m-tiles.
// 32x32x16 MFMA layouts: A/B: lane l -> k = 8*(l>>5)+e; A row / B col = l&31.
// C/D: col = l&31, row = (reg&3) + 8*(reg>>2) + 4*(l>>5).
// acc starts at 0; -||c||^2/2 subtracted at pack so argmin dist ==
// argmax (r.c - cn/2); codeword index packed into low 10 mantissa bits ->
// fmax-only running argmax.
// ---------------------------------------------------------------------------
__global__ __launch_bounds__(NTHREADS, 2)
void vq_search(const float* __restrict__ X,
               const char* __restrict__ wsb, const float* __restrict__ cnorm,
               unsigned short* __restrict__ IDX, float* __restrict__ wsmse) {
  __shared__ __align__(16) char  lds_cb[2][SUPER_BYTES];  // 2 x 32 KiB
  __shared__ unsigned short lds_idx[BLK_ROWS];            // 512 B
  __shared__ float lds_n[BLK_ROWS];                       // 1 KiB
  __shared__ float lds_msum[4];                           // 16 B

  const int tid  = threadIdx.x;
  const int wave = tid >> 6;           // 0..3
  const int lane = tid & 63;
  const int c32  = lane & 31;          // A row / B,D col within 32-tile
  const int hi   = lane >> 5;          // k-half (A,B) / row-offset (D)
  const int g0   = wave >> 1;          // group processed FIRST (owns staged frags)
  const int s0   = (wave & 1) * 8;     // fragment rotation offset

  const int rowbase = blockIdx.x * BLK_ROWS + wave * WROWS;

  // ---- initial approximate residual = bf16(x), A-fragment layout, ROTATED:
  // af[t][k] covers dims d = 16*((s0+k)&15) + 8*hi + e
  bf16x8 af[2][16];
#pragma unroll
  for (int t = 0; t < 2; ++t) {
    const float* px = X + (size_t)(rowbase + t * 32 + c32) * DIM + 8 * hi;
    float s2 = 0.f;
#pragma unroll
    for (int k = 0; k < 16; ++k) {
      const int s = (s0 + k) & 15;
      f32x4 a = *(const f32x4*)(px + 16 * s);
      f32x4 b = *(const f32x4*)(px + 16 * s + 4);
      bf16x8 tt;
#pragma unroll
      for (int e = 0; e < 4; ++e) {
        tt[e] = (__bf16)a[e]; tt[4 + e] = (__bf16)b[e];
        s2 += a[e] * a[e] + b[e] * b[e];
      }
      af[t][k] = tt;
    }
    // n0 = ||x||^2: lane's partial covers its k-half; pair with lane^32.
    float v = s2 + __shfl_xor(s2, 32);
    if (lane < 32) lds_n[wave * WROWS + t * 32 + c32] = v;
  }

  // ---- prologue: stage period 0 into buf0, drain, pre-read own 4 frags ----
#pragma unroll
  for (int i = 0; i < 8; ++i) {
    const int seg = (wave * 8 + i) * 1024;
    __builtin_amdgcn_global_load_lds(
        (const __attribute__((address_space(1))) char*)(wsb + seg + lane * 16),
        (__attribute__((address_space(3))) char*)(&lds_cb[0][0] + seg),
        16, 0, 0);
  }
  asm volatile("s_waitcnt vmcnt(0)" ::: "memory");
  __builtin_amdgcn_sched_barrier(0);
  bf16x8 pr[4];
  {
    const char* nb = &lds_cb[0][0] + g0 * 16384 + lane * 16;
#pragma unroll
    for (int k = 0; k < 4; ++k)
      pr[k] = *(const bf16x8*)(nb + (((s0 + k) & 15) << 10));
  }

#pragma unroll 1
  for (int st = 0; st < NSTAGE; ++st) {
    float mv[2][16];
#pragma unroll
    for (int t = 0; t < 2; ++t)
#pragma unroll
      for (int r = 0; r < 16; ++r) mv[t][r] = -3.402823466e38f;

#pragma unroll 1
    for (int p = 0; p < NPER_ST; ++p) {
      const int pf = st * NPER_ST + p;   // flat period 0..127

      __builtin_amdgcn_sched_barrier(0);
      __builtin_amdgcn_s_barrier();      // ONE barrier per 64 codewords
      __builtin_amdgcn_sched_barrier(0);

      // top-issue staging for period pf+1 into buf[(pf+1)&1].
      // Safety: that buffer's readers were period pf-1; all waves here have
      // passed barrier(pf), which follows those reads in every wave's
      // program order (reads are consumed by MFMAs before the pack that
      // precedes the barrier).
      if (pf + 1 < NPER_ALL) {
        const char* src = wsb + (size_t)(pf + 1) * SUPER_BYTES;
        char* dst = &lds_cb[(pf + 1) & 1][0];
#pragma unroll
        for (int i = 0; i < 8; ++i) {
          const int seg = (wave * 8 + i) * 1024;
          __builtin_amdgcn_global_load_lds(
              (const __attribute__((address_space(1))) char*)(src + seg + lane * 16),
              (__attribute__((address_space(3))) char*)(dst + seg),
              16, 0, 0);
        }
      }

      // cnorms (global, L1/L2-hit), consumed only at the packs
      const float cnF = cnorm[st * NCB + p * SUPER_CW + g0 * 32 + c32];
      const float cnS = cnorm[st * NCB + p * SUPER_CW + (1 - g0) * 32 + c32];

      const char* base = &lds_cb[pf & 1][0] + lane * 16;
      const char* bF = base + g0 * 16384;
      const char* bS = base + (1 - g0) * 16384;

      f32x16 acc0, acc1;
#pragma unroll
      for (int r = 0; r < 16; ++r) { acc0[r] = 0.f; acc1[r] = 0.f; }

      // ---- group FIRST (own-staged): k<4 from pre-read registers ----
      __builtin_amdgcn_s_setprio(1);
#pragma unroll
      for (int k = 0; k < 16; ++k) {
        bf16x8 b = (k < 4) ? pr[k]
                           : *(const bf16x8*)(bF + (((s0 + k) & 15) << 10));
        acc0 = __builtin_amdgcn_mfma_f32_32x32x16_bf16(af[0][k], b, acc0, 0, 0, 0);
        acc1 = __builtin_amdgcn_mfma_f32_32x32x16_bf16(af[1][k], b, acc1, 0, 0, 0);
      }
      __builtin_amdgcn_s_setprio(0);

      {  // pack first group
        const float cnh = 0.5f * cnF;
        const unsigned col = (unsigned)(p * SUPER_CW + g0 * 32 + c32);
#pragma unroll
        for (int r = 0; r < 16; ++r) {
          union { float f; unsigned u; } p0, p1;
          p0.f = acc0[r] - cnh; p0.u = (p0.u & 0xFFFFFC00u) | col;
          p1.f = acc1[r] - cnh; p1.u = (p1.u & 0xFFFFFC00u) | col;
          mv[0][r] = fmaxf(mv[0][r], p0.f);
          mv[1][r] = fmaxf(mv[1][r], p1.f);
        }
      }

      // ---- group SECOND (acc pair reused; WAR puts pack-first before it,
      //      the sibling block's waves cover the gap) ----
#pragma unroll
      for (int r = 0; r < 16; ++r) { acc0[r] = 0.f; acc1[r] = 0.f; }
      __builtin_amdgcn_s_setprio(1);
#pragma unroll
      for (int k = 0; k < 16; ++k) {
        bf16x8 b = *(const bf16x8*)(bS + (((s0 + k) & 15) << 10));
        acc0 = __builtin_amdgcn_mfma_f32_32x32x16_bf16(af[0][k], b, acc0, 0, 0, 0);
        acc1 = __builtin_amdgcn_mfma_f32_32x32x16_bf16(af[1][k], b, acc1, 0, 0, 0);
      }
      __builtin_amdgcn_s_setprio(0);

      {  // pack second group
        const float cnh = 0.5f * cnS;
        const unsigned col = (unsigned)(p * SUPER_CW + (1 - g0) * 32 + c32);
#pragma unroll
        for (int r = 0; r < 16; ++r) {
          union { float f; unsigned u; } p0, p1;
          p0.f = acc0[r] - cnh; p0.u = (p0.u & 0xFFFFFC00u) | col;
          p1.f = acc1[r] - cnh; p1.u = (p1.u & 0xFFFFFC00u) | col;
          mv[0][r] = fmaxf(mv[0][r], p0.f);
          mv[1][r] = fmaxf(mv[1][r], p1.f);
        }
      }

      // ---- bottom: drain own staging (guarantees buf[(pf+1)&1] complete
      //      for MY segments AND that my staging lands before barrier(pf+1)),
      //      then pre-read my own first 4 fragments of period pf+1 ----
      asm volatile("s_waitcnt vmcnt(0)" ::: "memory");
      __builtin_amdgcn_sched_barrier(0);
      if (pf + 1 < NPER_ALL) {
        const char* nb = &lds_cb[(pf + 1) & 1][0] + g0 * 16384 + lane * 16;
#pragma unroll
        for (int k = 0; k < 4; ++k)
          pr[k] = *(const bf16x8*)(nb + (((s0 + k) & 15) << 10));
      }
    }

    // ---- cross-lane argmax + ||r||^2 recursion ----
    // (t,r): row = t*32 + (r&3) + 8*(r>>2) + 4*hi ; reduce over the 32 cols
    float msum = 0.f;
#pragma unroll
    for (int t = 0; t < 2; ++t)
#pragma unroll
      for (int r = 0; r < 16; ++r) {
        float v = mv[t][r];
#pragma unroll
        for (int m = 1; m <= 16; m <<= 1) v = fmaxf(v, __shfl_xor(v, m));
        union { float f; unsigned u; } w; w.f = v;
        const float vtrue = __builtin_bit_cast(float, w.u & 0xFFFFFC00u);
        const int   row   = t * 32 + (r & 3) + 8 * (r >> 2) + 4 * hi;
        const int   wrow  = wave * WROWS + row;
        const float n_new = lds_n[wrow] - 2.0f * vtrue;   // min-dist identity
        msum += n_new;
        if (c32 == 0) {
          lds_n[wrow]   = n_new;
          const int ix = (int)(w.u & 1023u);
          lds_idx[wrow] = (unsigned short)ix;
          IDX[st * T_ROWS + rowbase + row] = (unsigned short)ix;
        }
      }
    // msum uniform within each 32-lane half; halves cover disjoint rows
    msum += __shfl_xor(msum, 32);
    if (lane == 0) lds_msum[wave] = msum;

    if (st != NSTAGE - 1) {
      // ---- approximate af update (ranking only) from the B-layout copy,
      //      rotation-consistent: af[t][k] -= codeword slice s=(s0+k)&15.
#pragma unroll
      for (int t = 0; t < 2; ++t) {
        const int idx = (int)lds_idx[wave * WROWS + t * 32 + c32];
        const char* q = wsb + (size_t)st * NCB * 512
                      + (size_t)(idx >> 5) * 16384 + hi * 512 + (idx & 31) * 16;
#pragma unroll
        for (int k = 0; k < 16; ++k) {
          bf16x8 qb = *(const bf16x8*)(q + (((s0 + k) & 15) << 10));
          bf16x8 tt = af[t][k];
#pragma unroll
          for (int e = 0; e < 8; ++e)
            tt[e] = (__bf16)((float)tt[e] - (float)qb[e]);
          af[t][k] = tt;
        }
      }
    }

    // stage-end barrier: orders lds_msum writes before the block reduce
    __builtin_amdgcn_s_barrier();

    // block-level MSE reduction: 1 atomic per block per stage
    if (wave == 0) {
      float v = (lane < 4) ? lds_msum[lane] : 0.f;
      v += __shfl_xor(v, 1);
      v += __shfl_xor(v, 2);
      if (lane == 0) atomicAdd(wsmse + st, v);
    }
  }
}

// ---------------------------------------------------------------------------
// Recon kernel: OUT[row] = sum of the 8 chosen bf16 codewords, read from the
// B-layout copy. 8 threads/row; thread g covers dims g*32..g*32+31:
//   dim d = g*32 + k*8  ->  s = 2g + (k>>1), hi = k&1
// ---------------------------------------------------------------------------
__global__ __launch_bounds__(256)
void vq_recon(const char* __restrict__ wsb, const unsigned short* __restrict__ IDX,
              float* __restrict__ OUT) {
  const int tid = threadIdx.x;
  const int row = blockIdx.x * (256 / 8) + (tid >> 3);
  const int g   = tid & 7;             // dims g*32 .. g*32+31

  int idxs[NSTAGE];
#pragma unroll
  for (int st = 0; st < NSTAGE; ++st) idxs[st] = IDX[st * T_ROWS + row];

  float a[32];
#pragma unroll
  for (int d = 0; d < 32; ++d) a[d] = 0.f;

#pragma unroll
  for (int st = 0; st < NSTAGE; ++st) {
    const char* q = wsb + (size_t)st * NCB * 512
                  + (size_t)(idxs[st] >> 5) * 16384 + (idxs[st] & 31) * 16;
#pragma unroll
    for (int k = 0; k < 4; ++k) {
      const int s  = 2 * g + (k >> 1);
      const int h2 = (k & 1);
      bf16x8 qb = *(const bf16x8*)(q + s * 1024 + h2 * 512);
#pragma unroll
      for (int e = 0; e < 8; ++e) a[k * 8 + e] += (float)qb[e];
    }
  }

  float* po = OUT + (size_t)row * DIM + g * 32;
#pragma unroll
  for (int m = 0; m < 8; ++m) {
    f32x4 o = {a[4 * m], a[4 * m + 1], a[4 * m + 2], a[4 * m + 3]};
    *(f32x4*)(po + 4 * m) = o;
  }
}

__global__ void vq_fin(const float* __restrict__ wsmse, float* __restrict__ OUT) {
  const int i = threadIdx.x;
  if (i < NSTAGE) {
    OUT[(size_t)T_ROWS * DIM + i] = wsmse[i] * (1.0f / ((float)T_ROWS * (float)DIM));
  }
}

extern "C" void kernel_launch(void* const* d_in, const int* in_sizes, int n_in,
                              void* d_out, int out_size, void* d_ws, size_t ws_size,
                              hipStream_t stream) {
  (void)in_sizes; (void)n_in; (void)out_size; (void)ws_size;
  const float* X  = (const float*)d_in[0];
  const float* CB = (const float*)d_in[1];
  float* OUT = (float*)d_out;
  char*  wsb   = (char*)d_ws;
  float* cnorm = (float*)((char*)d_ws + WS_CNORM_OFF);
  float* wsmse = (float*)((char*)d_ws + WS_MSE_OFF);
  unsigned short* IDX = (unsigned short*)((char*)d_ws + WS_IDX_OFF);

  hipMemsetAsync(wsmse, 0, NSTAGE * sizeof(float), stream);
  hipLaunchKernelGGL(vq_prep, dim3(1024), dim3(256), 0, stream,
                     CB, wsb, cnorm);
  hipLaunchKernelGGL(vq_search, dim3(T_ROWS / BLK_ROWS), dim3(NTHREADS), 0, stream,
                     X, wsb, cnorm, IDX, wsmse);
  hipLaunchKernelGGL(vq_recon, dim3(T_ROWS / (256 / 8)), dim3(256), 0, stream,
                     wsb, IDX, OUT);
  hipLaunchKernelGGL(vq_fin, dim3(1), dim3(64), 0, stream, wsmse, OUT);
}

// Round 8
// 804.826 us; speedup vs baseline: 2.8521x; 2.8521x over previous
//
#include <hip/hip_runtime.h>
#include <stdint.h>

// ProgressiveVQ: 8-stage residual VQ, T=131072 rows, D=256, K=1024 codewords/stage.
// out[0:T*D] = recon ; out[T*D..+8] = per-stage MSE (= mean(residual_i^2)).
//
// R8: r=1 at TRUE 4 waves/SIMD — the last untested cell.
//   * 4-wave (256-thr) blocks, 32 rows/wave (ONE 32-row m-tile).
//     State: af 64 + acc 16 (AGPR) + mv 16 + temps ~ 115 vs the 128/wave cap
//     at 4 waves/SIMD (R6 compiled this r=1 body to 76 VGPR — real margin,
//     unlike R2's 512-thread 64V/64A split or R3/R4/R7's r>=2 additions).
//   * __launch_bounds__(256,4); grid 1024 = 4 blocks/CU, WHOLE grid resident
//     (no tail). LDS 33.5 KB/block -> 4 x 33.5 = 134 KB/CU fits.
//   * 2 x 16 KB ring, depth-1: top-of-chunk barrier; staging for ch+1 issued
//     right after it into buf^1 (readers of that buffer were chunk ch-1 and
//     finished before barrier(ch)); own staging drained by vmcnt(0) at the
//     bottom, so barrier(ch+1) implies the buffer is fully staged. Staging
//     latency (L2 ~200-400 cyc; HBM first stage ~900) hides under the
//     ~1800-cyc contended compute window.
//   * flat B-FRAGMENT global layout (R6): staging linear (global_load_lds,
//     no swizzle), ds_reads linear conflict-free, prep write-coalesced;
//     cnorm read straight from global (consumed only at pack).
//   * acc zero-init; -||c||^2/2 deferred to pack; fmax-only argmax with the
//     codeword index packed into the low 10 mantissa bits.
//   bf16-carried residual (argmin near-ties only; validated earlier,
//   absmax <=4.5e-3). ||r||^2 recursion gives MSE free.

#define T_ROWS   131072
#define DIM      256
#define NSTAGE   8
#define NCB      1024
#define WROWS    32             // rows per wave (ONE 32-row m-tile)
#define NWAVE    4
#define BLK_ROWS (NWAVE * WROWS)   // 128 rows per block
#define NTHREADS 256
#define CHUNK_CW 32             // codewords per chunk
#define NCHUNK   (NCB / CHUNK_CW)          // 32 chunks/stage
#define NGCH     (NSTAGE * NCHUNK)         // 256 flat chunks
#define CHUNK_BYTES (CHUNK_CW * 512)       // 16384

// d_ws layout
#define WS_B_BYTES     (NSTAGE * NCB * 512)            // bf16 codebook, B-frag layout, 4 MiB
#define WS_CNORM_OFF   WS_B_BYTES
#define WS_CNORM_BYTES (NSTAGE * NCB * 4)
#define WS_MSE_OFF     (WS_CNORM_OFF + WS_CNORM_BYTES)
#define WS_IDX_OFF     (WS_MSE_OFF + 64)               // u16[NSTAGE][T_ROWS], 2 MiB

typedef __attribute__((ext_vector_type(8)))  short  s16x8;
typedef __attribute__((ext_vector_type(8)))  __bf16 bf16x8;
typedef __attribute__((ext_vector_type(4)))  float  f32x4;
typedef __attribute__((ext_vector_type(16))) float  f32x16;

__device__ __forceinline__ unsigned short f2bf(float f) {
  union { float f; unsigned u; } v; v.f = f;
  unsigned r = v.u + 0x7FFFu + ((v.u >> 16) & 1u);   // RNE
  return (unsigned short)(r >> 16);
}

// ---------------------------------------------------------------------------
// Preprocess (write-coalesced, R6). Phase 1: fp32 CB -> bf16 B-frag copy.
//   block b (0..1023): group g = b>>2 (32 codewords), s-quarter s0q = (b&3)*4.
//   thread: c32 = tid&31, sh = tid>>5 -> s = s0q + (sh>>1), hi = sh&1.
//   dst = wsb + g*16384 + s*1024 + hi*512 + c32*16 (contiguous 4KB per block).
// Phase 2: cnorm with coalesced reads + 32-thread shfl reduction.
// ---------------------------------------------------------------------------
__global__ void vq_prep(const float* __restrict__ CB, char* __restrict__ wsb,
                        float* __restrict__ cnorm) {
  const int tid = threadIdx.x;
  const int b   = blockIdx.x;
  // ---- phase 1: B-frag copy ----
  {
    const int g   = b >> 2;
    const int s0q = (b & 3) * 4;
    const int c32 = tid & 31;
    const int sh  = tid >> 5;
    const int s   = s0q + (sh >> 1);
    const int hi  = sh & 1;
    const int cw  = g * 32 + c32;          // global codeword (stage built in)
    const float* src = CB + (size_t)cw * DIM + 16 * s + 8 * hi;
    f32x4 a = *(const f32x4*)(src);
    f32x4 c = *(const f32x4*)(src + 4);
    s16x8 h;
#pragma unroll
    for (int e = 0; e < 4; ++e) { h[e] = (short)f2bf(a[e]); h[4 + e] = (short)f2bf(c[e]); }
    *(s16x8*)(wsb + (size_t)g * 16384 + s * 1024 + hi * 512 + c32 * 16) = h;
  }
  // ---- phase 2: cnorm ----
  {
    const int cwl = tid >> 5;
    const int j   = tid & 31;
    const int cw  = b * 8 + cwl;
    const float* src = CB + (size_t)cw * DIM + 8 * j;
    f32x4 a = *(const f32x4*)(src);
    f32x4 c = *(const f32x4*)(src + 4);
    float sq = a[0]*a[0] + a[1]*a[1] + a[2]*a[2] + a[3]*a[3]
             + c[0]*c[0] + c[1]*c[1] + c[2]*c[2] + c[3]*c[3];
#pragma unroll
    for (int m = 1; m <= 16; m <<= 1) sq += __shfl_xor(sq, m);   // 32-thread group
    if (j == 0) cnorm[cw] = sq;
  }
}

// ---------------------------------------------------------------------------
// Search kernel. 4 waves/block; wave owns ONE 32-row m-tile; 4 blocks/CU.
// 32x32x16 MFMA layouts: A/B: lane l -> k = 8*(l>>5)+e; A row / B col = l&31.
// C/D: col = l&31, row = (reg&3) + 8*(reg>>2) + 4*(l>>5).
// acc starts at 0; -||c||^2/2 subtracted at pack so argmin dist ==
// argmax (r.c - cn/2); codeword index packed into low 10 mantissa bits ->
// fmax-only running argmax.
// ---------------------------------------------------------------------------
__global__ __launch_bounds__(NTHREADS, 4)
void vq_search(const float* __restrict__ X,
               const char* __restrict__ wsb, const float* __restrict__ cnorm,
               unsigned short* __restrict__ IDX, float* __restrict__ wsmse) {
  __shared__ __align__(16) char  lds_cb[2][CHUNK_BYTES];  // 32 KiB ring
  __shared__ unsigned short lds_idx[BLK_ROWS];            // 256 B
  __shared__ float lds_n[BLK_ROWS];                       // 512 B
  __shared__ float lds_msum[NWAVE];                       // 16 B

  const int tid  = threadIdx.x;
  const int wave = tid >> 6;           // 0..3
  const int lane = tid & 63;
  const int c32  = lane & 31;          // A row / B,D col within 32-tile
  const int hi   = lane >> 5;          // k-half (A,B) / row-offset (D)

  const int rowbase = blockIdx.x * BLK_ROWS + wave * WROWS;

  // ---- initial approximate residual = bf16(x), A-fragment layout ----
  // lane holds row rowbase + c32; step s covers dims d = 16*s + 8*hi + e
  bf16x8 af[16];
  {
    const float* px = X + (size_t)(rowbase + c32) * DIM + 8 * hi;
    float s2 = 0.f;
#pragma unroll
    for (int s = 0; s < 16; ++s) {
      f32x4 a = *(const f32x4*)(px + 16 * s);
      f32x4 b = *(const f32x4*)(px + 16 * s + 4);
      bf16x8 tt;
#pragma unroll
      for (int e = 0; e < 4; ++e) {
        tt[e] = (__bf16)a[e]; tt[4 + e] = (__bf16)b[e];
        s2 += a[e] * a[e] + b[e] * b[e];
      }
      af[s] = tt;
    }
    // n0 = ||x||^2: lane's partial covers its k-half; pair with lane^32.
    float v = s2 + __shfl_xor(s2, 32);
    if (lane < 32) lds_n[wave * WROWS + c32] = v;
  }

  // ---- prologue: stage flat chunk 0 into slot 0, drain ----
#pragma unroll
  for (int i = 0; i < 4; ++i) {
    const int seg = (wave * 4 + i) * 1024;
    __builtin_amdgcn_global_load_lds(
        (const __attribute__((address_space(1))) char*)(wsb + seg + lane * 16),
        (__attribute__((address_space(3))) char*)(&lds_cb[0][0] + seg),
        16, 0, 0);
  }
  asm volatile("s_waitcnt vmcnt(0)" ::: "memory");
  __builtin_amdgcn_sched_barrier(0);

#pragma unroll 1
  for (int st = 0; st < NSTAGE; ++st) {
    float mv[16];
#pragma unroll
    for (int r = 0; r < 16; ++r) mv[r] = -3.402823466e38f;

#pragma unroll 1
    for (int ch = 0; ch < NCHUNK; ++ch) {
      const int gf = st * NCHUNK + ch;           // flat chunk 0..255

      // top-of-chunk barrier: buf[gf&1] fully staged (every wave drained its
      // own staging with vmcnt(0) before reaching this barrier).
      __builtin_amdgcn_sched_barrier(0);
      __builtin_amdgcn_s_barrier();
      __builtin_amdgcn_sched_barrier(0);

      // issue staging for chunk gf+1 into buf[(gf+1)&1].
      // Safety: that buffer held chunk gf-1; all its readers finished before
      // barrier(gf) (reads precede each wave's bottom vmcnt+barrier).
      if (gf + 1 < NGCH) {
        const char* src = wsb + (size_t)(gf + 1) * CHUNK_BYTES;
        char* dst = &lds_cb[(gf + 1) & 1][0];
#pragma unroll
        for (int i = 0; i < 4; ++i) {
          const int seg = (wave * 4 + i) * 1024;
          __builtin_amdgcn_global_load_lds(
              (const __attribute__((address_space(1))) char*)(src + seg + lane * 16),
              (__attribute__((address_space(3))) char*)(dst + seg),
              16, 0, 0);
        }
      }

      // cn: coalesced 128B global read, consumed only at pack time
      const float cnv = cnorm[gf * CHUNK_CW + c32];

      f32x16 acc;
#pragma unroll
      for (int r = 0; r < 16; ++r) acc[r] = 0.f;

      const char* buf = &lds_cb[gf & 1][0] + lane * 16;
      __builtin_amdgcn_s_setprio(1);
#pragma unroll
      for (int s = 0; s < 16; ++s) {
        bf16x8 b = *(const bf16x8*)(buf + s * 1024);   // linear, conflict-free
        acc = __builtin_amdgcn_mfma_f32_32x32x16_bf16(af[s], b, acc, 0, 0, 0);
      }
      __builtin_amdgcn_s_setprio(0);

      // pack: p = (r.c - cn/2) with codeword index in low 10 mantissa bits
      const float cnh = 0.5f * cnv;
      const unsigned col = (unsigned)(ch * CHUNK_CW + c32);
#pragma unroll
      for (int r = 0; r < 16; ++r) {
        union { float f; unsigned u; } p;
        p.f = acc[r] - cnh;
        p.u = (p.u & 0xFFFFFC00u) | col;
        mv[r] = fmaxf(mv[r], p.f);
      }

      // bottom: drain own staging so barrier(gf+1) implies buf fully staged
      asm volatile("s_waitcnt vmcnt(0)" ::: "memory");
      __builtin_amdgcn_sched_barrier(0);
    }

    // ---- cross-lane argmax + ||r||^2 recursion ----
    // r: row = (r&3) + 8*(r>>2) + 4*hi ; reduce over the 32 cols
    float msum = 0.f;
#pragma unroll
    for (int r = 0; r < 16; ++r) {
      float v = mv[r];
#pragma unroll
      for (int m = 1; m <= 16; m <<= 1) v = fmaxf(v, __shfl_xor(v, m));
      union { float f; unsigned u; } w; w.f = v;
      const float vtrue = __builtin_bit_cast(float, w.u & 0xFFFFFC00u);
      const int   row   = (r & 3) + 8 * (r >> 2) + 4 * hi;
      const int   wrow  = wave * WROWS + row;
      const float n_new = lds_n[wrow] - 2.0f * vtrue;   // min-dist identity
      msum += n_new;
      if (c32 == 0) {
        lds_n[wrow]   = n_new;
        const int ix = (int)(w.u & 1023u);
        lds_idx[wrow] = (unsigned short)ix;
        IDX[st * T_ROWS + rowbase + row] = (unsigned short)ix;
      }
    }
    // msum uniform within each 32-lane half; halves cover disjoint rows
    msum += __shfl_xor(msum, 32);
    if (lane == 0) lds_msum[wave] = msum;

    if (st != NSTAGE - 1) {
      // ---- approximate af update (ranking only) from the B-layout copy:
      //      dims d=16s+8hi+e of codeword idx live at
      //      wsb + st*512K + (idx>>5)*16384 + s*1024 + hi*512 + (idx&31)*16
      const int idx = (int)lds_idx[wave * WROWS + c32];
      const char* q = wsb + (size_t)st * NCB * 512
                    + (size_t)(idx >> 5) * 16384 + hi * 512 + (idx & 31) * 16;
#pragma unroll
      for (int s = 0; s < 16; ++s) {
        bf16x8 qb = *(const bf16x8*)(q + s * 1024);
        bf16x8 tt = af[s];
#pragma unroll
        for (int e = 0; e < 8; ++e)
          tt[e] = (__bf16)((float)tt[e] - (float)qb[e]);
        af[s] = tt;
      }
    }

    // stage-end barrier: orders lds_msum writes before the block reduce
    __builtin_amdgcn_s_barrier();

    // block-level MSE reduction: 1 atomic per block per stage
    if (wave == 0) {
      float v = (lane < NWAVE) ? lds_msum[lane] : 0.f;
      v += __shfl_xor(v, 1);
      v += __shfl_xor(v, 2);
      if (lane == 0) atomicAdd(wsmse + st, v);
    }
  }
}

// ---------------------------------------------------------------------------
// Recon kernel: OUT[row] = sum of the 8 chosen bf16 codewords, read from the
// B-layout copy. 8 threads/row; thread g covers dims g*32..g*32+31:
//   dim d = g*32 + k*8  ->  s = 2g + (k>>1), hi = k&1
// ---------------------------------------------------------------------------
__global__ __launch_bounds__(256)
void vq_recon(const char* __restrict__ wsb, const unsigned short* __restrict__ IDX,
              float* __restrict__ OUT) {
  const int tid = threadIdx.x;
  const int row = blockIdx.x * (256 / 8) + (tid >> 3);
  const int g   = tid & 7;             // dims g*32 .. g*32+31

  int idxs[NSTAGE];
#pragma unroll
  for (int st = 0; st < NSTAGE; ++st) idxs[st] = IDX[st * T_ROWS + row];

  float a[32];
#pragma unroll
  for (int d = 0; d < 32; ++d) a[d] = 0.f;

#pragma unroll
  for (int st = 0; st < NSTAGE; ++st) {
    const char* q = wsb + (size_t)st * NCB * 512
                  + (size_t)(idxs[st] >> 5) * 16384 + (idxs[st] & 31) * 16;
#pragma unroll
    for (int k = 0; k < 4; ++k) {
      const int s  = 2 * g + (k >> 1);
      const int h2 = (k & 1);
      bf16x8 qb = *(const bf16x8*)(q + s * 1024 + h2 * 512);
#pragma unroll
      for (int e = 0; e < 8; ++e) a[k * 8 + e] += (float)qb[e];
    }
  }

  float* po = OUT + (size_t)row * DIM + g * 32;
#pragma unroll
  for (int m = 0; m < 8; ++m) {
    f32x4 o = {a[4 * m], a[4 * m + 1], a[4 * m + 2], a[4 * m + 3]};
    *(f32x4*)(po + 4 * m) = o;
  }
}

__global__ void vq_fin(const float* __restrict__ wsmse, float* __restrict__ OUT) {
  const int i = threadIdx.x;
  if (i < NSTAGE) {
    OUT[(size_t)T_ROWS * DIM + i] = wsmse[i] * (1.0f / ((float)T_ROWS * (float)DIM));
  }
}

extern "C" void kernel_launch(void* const* d_in, const int* in_sizes, int n_in,
                              void* d_out, int out_size, void* d_ws, size_t ws_size,
                              hipStream_t stream) {
  (void)in_sizes; (void)n_in; (void)out_size; (void)ws_size;
  const float* X  = (const float*)d_in[0];
  const float* CB = (const float*)d_in[1];
  float* OUT = (float*)d_out;
  char*  wsb   = (char*)d_ws;
  float* cnorm = (float*)((char*)d_ws + WS_CNORM_OFF);
  float* wsmse = (float*)((char*)d_ws + WS_MSE_OFF);
  unsigned short* IDX = (unsigned short*)((char*)d_ws + WS_IDX_OFF);

  hipMemsetAsync(wsmse, 0, NSTAGE * sizeof(float), stream);
  hipLaunchKernelGGL(vq_prep, dim3(1024), dim3(256), 0, stream,
                     CB, wsb, cnorm);
  hipLaunchKernelGGL(vq_search, dim3(T_ROWS / BLK_ROWS), dim3(NTHREADS), 0, stream,
                     X, wsb, cnorm, IDX, wsmse);
  hipLaunchKernelGGL(vq_recon, dim3(T_ROWS / (256 / 8)), dim3(256), 0, stream,
                     wsb, IDX, OUT);
  hipLaunchKernelGGL(vq_fin, dim3(1), dim3(64), 0, stream, wsmse, OUT);
}